// Round 21
// baseline (81.592 us; speedup 1.0000x reference)
//
#include <hip/hip_runtime.h>
#include <hip/hip_bf16.h>

typedef unsigned short u16;
typedef unsigned int   u32;
typedef __attribute__((ext_vector_type(8))) short bf16x8;
typedef __attribute__((ext_vector_type(4))) float f32x4;

__device__ __forceinline__ float bflo(u32 w) { return __uint_as_float(w << 16); }
__device__ __forceinline__ float bfhi(u32 w) { return __uint_as_float(w & 0xffff0000u); }
__device__ __forceinline__ u16 f2bf(float f) {           // cold path (prep kernel only)
    u32 u = __float_as_uint(f);
    return (u16)((u + 0x7fffu + ((u >> 16) & 1u)) >> 16);
}
// hot-path pair conversion: RNE via ISel (R15-proven; NOT inline asm — R11 lesson)
__device__ __forceinline__ u32 pk2(float lo, float hi) {
    union { __hip_bfloat162 h; u32 u; } cvt;
    cvt.h = __float22bfloat162_rn(make_float2(lo, hi));   // lo -> bits[15:0], hi -> [31:16]
    return cvt.u;
}

constexpr int QK_STR = 40;   // halfwords per q/k row
constexpr int VT_STR = 72;   // halfwords per vT row
constexpr int PW_STR = 72;   // halfwords per per-wave p/o row
constexpr int XS_STR = 136;  // halfwords per xstage row

// workspace u16 layout (total 262,144 B — proven footprint):
//   [0,49152)        qkv_w bf16 (q rows pre-scaled by 32^-0.5)
//   [49152,65536)    proj_w bf16
//   [65536,131072)   bias+mask table, packed bf16 pairs: uint2 per [cls4][h4][mt4][nt4][lane64]
__global__ void prep_kernel(const float* __restrict__ qkv_w,
                            const float* __restrict__ proj_w,
                            const float* __restrict__ mask,
                            const float* __restrict__ rpb,
                            const int*   __restrict__ rel,
                            u16* __restrict__ ws,
                            uint2* __restrict__ ftab)
{
    int i = blockIdx.x * 256 + threadIdx.x;
    if (i < 49152) {
        float v = qkv_w[i];
        if (i < 16384) v *= 0.17677669529663687f;   // fold q-scale into Wq
        ws[i] = f2bf(v);
    }
    if (i < 16384) ws[49152 + i] = f2bf(proj_w[i]);
    if (i < 16384) {                                 // C-layout bias table (bf16-packed)
        int lane = i & 63, e = i >> 6;
        int nt = e & 3, mt = (e >> 2) & 3, h = (e >> 4) & 3, cls = e >> 6;
        int lr = lane & 15, lg = lane >> 4;
        int col = nt * 16 + lr;
        int rep = ((cls & 2) ? 240 : 0) + ((cls & 1) ? 15 : 0);  // representative window
        float vj[4];
#pragma unroll
        for (int j = 0; j < 4; ++j) {
            int row = mt * 16 + lg * 4 + j;
            float val;
            if (col >= 49)      val = -30000.f;  // padded K-token: exp -> exact 0
            else if (row >= 49) val = 0.f;       // padded Q-row: discarded later
            else val = rpb[rel[row * 49 + col] * 4 + h] + mask[(rep * 49 + row) * 49 + col];
            vj[j] = val;
        }
        uint2 pk;
        pk.x = (u32)f2bf(vj[0]) | ((u32)f2bf(vj[1]) << 16);
        pk.y = (u32)f2bf(vj[2]) | ((u32)f2bf(vj[3]) << 16);
        ftab[i] = pk;
    }
}

__global__ __launch_bounds__(512, 4)
void swin_mfma(const float* __restrict__ x,
               const float* __restrict__ qkv_b,
               const float* __restrict__ proj_b,
               const u16*   __restrict__ wqkv,
               const u16*   __restrict__ wproj,
               const uint2* __restrict__ ft2,
               float* __restrict__ out)
{
    __shared__ __align__(16) u16 q_s[4 * 64 * QK_STR];   // 20480 B
    __shared__ __align__(16) u16 k_s[4 * 64 * QK_STR];   // 20480 B
    __shared__ __align__(16) u16 vT_s[4 * 32 * VT_STR];  // 18432 B
    __shared__ __align__(16) u16 pB[8 * 16 * PW_STR];    // 18432 B: xstage, then per-wave P/O
    u16* const xs = pB;                                  //   total 77824 B -> 2 blocks/CU

    const int tid  = threadIdx.x;
    const int w    = tid >> 6;          // wave 0..7
    const int lane = tid & 63;
    const int lr   = lane & 15;
    const int lg   = lane >> 4;
    const int bid  = blockIdx.x;
    const int b    = bid >> 8;
    const int wi   = bid & 255;
    const int wh   = wi >> 4, ww = wi & 15;
    const int cls  = ((wh == 15) ? 2 : 0) | ((ww == 15) ? 1 : 0);

    const int mt = w & 3;               // wave's M-tile (stages 2,3)
    const int hp = w >> 2;              // head-pair (stage 2) / N-half (stage 3)

    // ---------------- stage 0: cooperative x window load -> LDS bf16 ----------------
    for (int idx = tid; idx < 49 * 32; idx += 512) {
        int t = idx >> 5, c4 = (idx & 31) << 2;
        int tr = t / 7, tc = t - tr * 7;
        int hs = wh * 7 + tr + 3; if (hs >= 112) hs -= 112;
        int cs = ww * 7 + tc + 3; if (cs >= 112) cs -= 112;
        float4 xv = *(const float4*)&x[((b * 112 + hs) * 112 + cs) * 128 + c4];
        *(uint2*)&xs[t * XS_STR + c4] = make_uint2(pk2(xv.x, xv.y), pk2(xv.z, xv.w));
    }
    __syncthreads();

    // ---------------- stage 1: QKV GEMM; A-frags from LDS, 3 n-tiles/wave ----------------
    bf16x8 a[4][4];
#pragma unroll
    for (int mt2 = 0; mt2 < 4; ++mt2) {
        bool valid = (mt2 * 16 + lr) < 49;
#pragma unroll
        for (int kt = 0; kt < 4; ++kt) {
            bf16x8 f = {0, 0, 0, 0, 0, 0, 0, 0};
            if (valid)
                f = *(const bf16x8*)&xs[(mt2 * 16 + lr) * XS_STR + kt * 32 + lg * 8];
            a[mt2][kt] = f;
        }
    }

#pragma unroll
    for (int t = 0; t < 3; ++t) {
        int n0 = w * 48 + t * 16;                 // uniform per wave
        bf16x8 bw[4];
#pragma unroll
        for (int kt = 0; kt < 4; ++kt)
            bw[kt] = *(const bf16x8*)&wqkv[(n0 + lr) * 128 + kt * 32 + lg * 8];
        float bias = qkv_b[n0 + lr];
        int which = n0 >> 7;                      // 0=q 1=k 2=v (uniform)
        if (which == 0) bias *= 0.17677669529663687f;
        int h = (n0 & 127) >> 5;
        int d = (n0 & 31) + lr;
        f32x4 ci = {bias, bias, bias, bias};      // bias as MFMA C-init (same col per lane)
#pragma unroll
        for (int mt2 = 0; mt2 < 4; ++mt2) {
            f32x4 acc = ci;
            // T5: favor this wave's MFMA burst over the co-resident block's load waves
            __builtin_amdgcn_s_setprio(1);
#pragma unroll
            for (int kt = 0; kt < 4; ++kt)
                acc = __builtin_amdgcn_mfma_f32_16x16x32_bf16(a[mt2][kt], bw[kt], acc, 0, 0, 0);
            __builtin_amdgcn_s_setprio(0);
            u32 r01 = pk2(acc[0], acc[1]);
            u32 r23 = pk2(acc[2], acc[3]);
            if (which == 2) {
                *(uint2*)&vT_s[(h * 32 + d) * VT_STR + mt2 * 16 + lg * 4] =
                    make_uint2(r01, r23);         // V^T, 4 contiguous token-cols
            } else {
                u16* dst = (which == 0) ? q_s : k_s;
                int rb = (h * 64 + mt2 * 16 + lg * 4) * QK_STR + d;
                dst[rb]              = (u16)r01;
                dst[rb + QK_STR]     = (u16)(r01 >> 16);
                dst[rb + 2 * QK_STR] = (u16)r23;
                dst[rb + 3 * QK_STR] = (u16)(r23 >> 16);
            }
        }
    }
    __syncthreads();

    // ---------------- stage 2: attention; wave = (mt, head-pair hp); no internal barrier ----
    float  invs[2][4];
    bf16x8 ap[2][2];
    u16* const pw = pB + w * 16 * PW_STR;         // this wave's private P/O region
#pragma unroll
    for (int hl = 0; hl < 2; ++hl) {
        int h = hp * 2 + hl;
        bf16x8 aq = *(const bf16x8*)&q_s[(h * 64 + mt * 16 + lr) * QK_STR + lg * 8];
        int eb = ((cls * 4 + h) * 4 + mt) * 4;
        f32x4 sc[4];
        __builtin_amdgcn_s_setprio(1);            // T5: QK^T MFMA cluster
#pragma unroll
        for (int nt = 0; nt < 4; ++nt) {
            bf16x8 bk = *(const bf16x8*)&k_s[(h * 64 + nt * 16 + lr) * QK_STR + lg * 8];
            uint2 cv = ft2[(eb + nt) * 64 + lane];             // bias+mask, bf16-packed C-layout
            f32x4 ci = {bflo(cv.x), bfhi(cv.x), bflo(cv.y), bfhi(cv.y)};
            sc[nt] = __builtin_amdgcn_mfma_f32_16x16x32_bf16(aq, bk, ci, 0, 0, 0);
        }
        __builtin_amdgcn_s_setprio(0);
#pragma unroll
        for (int j = 0; j < 4; ++j) {
            // no max-subtract: scores bounded (|qk| small, bias ~0.02), masked -> exp==0
            float p0 = __expf(sc[0][j]), p1 = __expf(sc[1][j]);
            float p2 = __expf(sc[2][j]), p3 = __expf(sc[3][j]);
            float sm = (p0 + p1) + (p2 + p3);
            sm += __shfl_xor(sm, 1);
            sm += __shfl_xor(sm, 2);
            sm += __shfl_xor(sm, 4);
            sm += __shfl_xor(sm, 8);
            invs[hl][j] = 1.f / sm;
            u32 r01 = pk2(p0, p1), r23 = pk2(p2, p3);
            u16* pr = pw + (lg * 4 + j) * PW_STR;
            pr[lr]      = (u16)r01;
            pr[lr + 16] = (u16)(r01 >> 16);
            pr[lr + 32] = (u16)r23;
            pr[lr + 48] = (u16)(r23 >> 16);
        }
        // transpose P back (own rows, same wave: in-order DS, no barrier)
        ap[hl][0] = *(const bf16x8*)&pw[lr * PW_STR + lg * 8];
        ap[hl][1] = *(const bf16x8*)&pw[lr * PW_STR + 32 + lg * 8];
    }
    // PV + O into the wave's own (fully consumed) P region
#pragma unroll
    for (int hl = 0; hl < 2; ++hl) {
        int h = hp * 2 + hl;
#pragma unroll
        for (int nt = 0; nt < 2; ++nt) {
            bf16x8 bv0 = *(const bf16x8*)&vT_s[(h * 32 + nt * 16 + lr) * VT_STR + lg * 8];
            bf16x8 bv1 = *(const bf16x8*)&vT_s[(h * 32 + nt * 16 + lr) * VT_STR + 32 + lg * 8];
            f32x4 z = {0.f, 0.f, 0.f, 0.f};
            __builtin_amdgcn_s_setprio(1);        // T5: PV MFMA pair
            f32x4 o = __builtin_amdgcn_mfma_f32_16x16x32_bf16(ap[hl][0], bv0, z, 0, 0, 0);
            o = __builtin_amdgcn_mfma_f32_16x16x32_bf16(ap[hl][1], bv1, o, 0, 0, 0);
            __builtin_amdgcn_s_setprio(0);
            u32 r01 = pk2(o[0] * invs[hl][0], o[1] * invs[hl][1]);
            u32 r23 = pk2(o[2] * invs[hl][2], o[3] * invs[hl][3]);
            int cbase = hl * 32 + nt * 16 + lr;    // local col 0..63
            pw[(lg * 4 + 0) * PW_STR + cbase] = (u16)r01;
            pw[(lg * 4 + 1) * PW_STR + cbase] = (u16)(r01 >> 16);
            pw[(lg * 4 + 2) * PW_STR + cbase] = (u16)r23;
            pw[(lg * 4 + 3) * PW_STR + cbase] = (u16)(r23 >> 16);
        }
    }
    __syncthreads();

    // ---------------- stage 3: proj; O read from per-wave regions ----------------
    bf16x8 ao[4];
#pragma unroll
    for (int kt = 0; kt < 4; ++kt) {
        int srcw = (kt >> 1) * 4 + mt;            // region owner: wave (hp = kt>>1, same mt)
        ao[kt] = *(const bf16x8*)&pB[(srcw * 16 + lr) * PW_STR + (kt & 1) * 32 + lg * 8];
    }
    int obase[4];
#pragma unroll
    for (int j = 0; j < 4; ++j) {
        int tok = mt * 16 + lg * 4 + j;
        if (tok < 49) {
            int tr = tok / 7, tc = tok - tr * 7;
            int hs = wh * 7 + tr + 3; if (hs >= 112) hs -= 112;
            int cs = ww * 7 + tc + 3; if (cs >= 112) cs -= 112;
            obase[j] = ((b * 112 + hs) * 112 + cs) * 128;
        } else obase[j] = -1;
    }
#pragma unroll
    for (int tn = 0; tn < 4; ++tn) {
        int n0 = (hp * 4 + tn) * 16;
        bf16x8 bw[4];
#pragma unroll
        for (int kt = 0; kt < 4; ++kt)
            bw[kt] = *(const bf16x8*)&wproj[(n0 + lr) * 128 + kt * 32 + lg * 8];
        float bias = proj_b[n0 + lr];
        f32x4 acc = {bias, bias, bias, bias};     // bias as C-init
        __builtin_amdgcn_s_setprio(1);            // T5: proj MFMA chain
#pragma unroll
        for (int kt = 0; kt < 4; ++kt)
            acc = __builtin_amdgcn_mfma_f32_16x16x32_bf16(ao[kt], bw[kt], acc, 0, 0, 0);
        __builtin_amdgcn_s_setprio(0);
#pragma unroll
        for (int j = 0; j < 4; ++j)
            if (obase[j] >= 0) out[obase[j] + n0 + lr] = acc[j];
    }
}

extern "C" void kernel_launch(void* const* d_in, const int* in_sizes, int n_in,
                              void* d_out, int out_size, void* d_ws, size_t ws_size,
                              hipStream_t stream) {
    (void)in_sizes; (void)n_in; (void)out_size; (void)ws_size;
    const float* x      = (const float*)d_in[0];
    const float* mask   = (const float*)d_in[1];
    const float* qkv_w  = (const float*)d_in[2];
    const float* qkv_b  = (const float*)d_in[3];
    const float* proj_w = (const float*)d_in[4];
    const float* proj_b = (const float*)d_in[5];
    const float* rpb    = (const float*)d_in[6];
    const int*   rel    = (const int*)d_in[7];
    float* out = (float*)d_out;

    u16*   ws16 = (u16*)d_ws;
    uint2* ftab = (uint2*)(ws16 + 65536);   // bytes [131072, 262144) — within proven footprint

    prep_kernel<<<dim3(192), dim3(256), 0, stream>>>(qkv_w, proj_w, mask, rpb, rel, ws16, ftab);
    swin_mfma<<<dim3(2048), dim3(512), 0, stream>>>(
        x, qkv_b, proj_b, ws16, ws16 + 49152, ftab, out);
}

// Round 22
// 77.935 us; speedup vs baseline: 1.0469x; 1.0469x over previous
//
#include <hip/hip_runtime.h>
#include <hip/hip_bf16.h>

typedef unsigned short u16;
typedef unsigned int   u32;
typedef __attribute__((ext_vector_type(8))) short bf16x8;
typedef __attribute__((ext_vector_type(4))) float f32x4;

__device__ __forceinline__ float bflo(u32 w) { return __uint_as_float(w << 16); }
__device__ __forceinline__ float bfhi(u32 w) { return __uint_as_float(w & 0xffff0000u); }
__device__ __forceinline__ u16 f2bf(float f) {           // cold path (prep kernel only)
    u32 u = __float_as_uint(f);
    return (u16)((u + 0x7fffu + ((u >> 16) & 1u)) >> 16);
}
// hot-path pair conversion: RNE via ISel (R15-proven; NOT inline asm — R11 lesson)
__device__ __forceinline__ u32 pk2(float lo, float hi) {
    union { __hip_bfloat162 h; u32 u; } cvt;
    cvt.h = __float22bfloat162_rn(make_float2(lo, hi));   // lo -> bits[15:0], hi -> [31:16]
    return cvt.u;
}

constexpr int QK_STR = 40;   // halfwords per q/k row
constexpr int VT_STR = 72;   // halfwords per vT row
constexpr int PW_STR = 72;   // halfwords per per-wave p/o row
constexpr int XS_STR = 136;  // halfwords per xstage row

// workspace u16 layout (total 262,144 B — proven footprint):
//   [0,49152)        qkv_w bf16 (q rows pre-scaled by 32^-0.5)
//   [49152,65536)    proj_w bf16
//   [65536,131072)   bias+mask table, packed bf16 pairs: uint2 per [cls4][h4][mt4][nt4][lane64]
__global__ void prep_kernel(const float* __restrict__ qkv_w,
                            const float* __restrict__ proj_w,
                            const float* __restrict__ mask,
                            const float* __restrict__ rpb,
                            const int*   __restrict__ rel,
                            u16* __restrict__ ws,
                            uint2* __restrict__ ftab)
{
    int i = blockIdx.x * 256 + threadIdx.x;
    if (i < 49152) {
        float v = qkv_w[i];
        if (i < 16384) v *= 0.17677669529663687f;   // fold q-scale into Wq
        ws[i] = f2bf(v);
    }
    if (i < 16384) ws[49152 + i] = f2bf(proj_w[i]);
    if (i < 16384) {                                 // C-layout bias table (bf16-packed)
        int lane = i & 63, e = i >> 6;
        int nt = e & 3, mt = (e >> 2) & 3, h = (e >> 4) & 3, cls = e >> 6;
        int lr = lane & 15, lg = lane >> 4;
        int col = nt * 16 + lr;
        int rep = ((cls & 2) ? 240 : 0) + ((cls & 1) ? 15 : 0);  // representative window
        float vj[4];
#pragma unroll
        for (int j = 0; j < 4; ++j) {
            int row = mt * 16 + lg * 4 + j;
            float val;
            if (col >= 49)      val = -30000.f;  // padded K-token: exp -> exact 0
            else if (row >= 49) val = 0.f;       // padded Q-row: discarded later
            else val = rpb[rel[row * 49 + col] * 4 + h] + mask[(rep * 49 + row) * 49 + col];
            vj[j] = val;
        }
        uint2 pk;
        pk.x = (u32)f2bf(vj[0]) | ((u32)f2bf(vj[1]) << 16);
        pk.y = (u32)f2bf(vj[2]) | ((u32)f2bf(vj[3]) << 16);
        ftab[i] = pk;
    }
}

__global__ __launch_bounds__(512, 4)
void swin_mfma(const float* __restrict__ x,
               const float* __restrict__ qkv_b,
               const float* __restrict__ proj_b,
               const u16*   __restrict__ wqkv,
               const u16*   __restrict__ wproj,
               const uint2* __restrict__ ft2,
               float* __restrict__ out)
{
    __shared__ __align__(16) u16 q_s[4 * 64 * QK_STR];   // 20480 B
    __shared__ __align__(16) u16 k_s[4 * 64 * QK_STR];   // 20480 B
    __shared__ __align__(16) u16 vT_s[4 * 32 * VT_STR];  // 18432 B
    __shared__ __align__(16) u16 pB[8 * 16 * PW_STR];    // 18432 B: xstage, then per-wave P/O
    u16* const xs = pB;                                  //   total 77824 B -> 2 blocks/CU

    const int tid  = threadIdx.x;
    const int w    = tid >> 6;          // wave 0..7
    const int lane = tid & 63;
    const int lr   = lane & 15;
    const int lg   = lane >> 4;
    const int bid  = blockIdx.x;
    const int b    = bid >> 8;
    const int wi   = bid & 255;
    const int wh   = wi >> 4, ww = wi & 15;
    const int cls  = ((wh == 15) ? 2 : 0) | ((ww == 15) ? 1 : 0);

    const int mt = w & 3;               // wave's M-tile (stages 2,3)
    const int hp = w >> 2;              // head-pair (stage 2) / N-half (stage 3)

    // ---------------- stage 0: cooperative x window load -> LDS bf16 ----------------
    for (int idx = tid; idx < 49 * 32; idx += 512) {
        int t = idx >> 5, c4 = (idx & 31) << 2;
        int tr = t / 7, tc = t - tr * 7;
        int hs = wh * 7 + tr + 3; if (hs >= 112) hs -= 112;
        int cs = ww * 7 + tc + 3; if (cs >= 112) cs -= 112;
        float4 xv = *(const float4*)&x[((b * 112 + hs) * 112 + cs) * 128 + c4];
        *(uint2*)&xs[t * XS_STR + c4] = make_uint2(pk2(xv.x, xv.y), pk2(xv.z, xv.w));
    }
    __syncthreads();

    // ---------------- stage 1: QKV GEMM; A-frags from LDS, 3 n-tiles/wave ----------------
    bf16x8 a[4][4];
#pragma unroll
    for (int mt2 = 0; mt2 < 4; ++mt2) {
        bool valid = (mt2 * 16 + lr) < 49;
#pragma unroll
        for (int kt = 0; kt < 4; ++kt) {
            bf16x8 f = {0, 0, 0, 0, 0, 0, 0, 0};
            if (valid)
                f = *(const bf16x8*)&xs[(mt2 * 16 + lr) * XS_STR + kt * 32 + lg * 8];
            a[mt2][kt] = f;
        }
    }

#pragma unroll
    for (int t = 0; t < 3; ++t) {
        int n0 = w * 48 + t * 16;                 // uniform per wave
        bf16x8 bw[4];
#pragma unroll
        for (int kt = 0; kt < 4; ++kt)
            bw[kt] = *(const bf16x8*)&wqkv[(n0 + lr) * 128 + kt * 32 + lg * 8];
        float bias = qkv_b[n0 + lr];
        int which = n0 >> 7;                      // 0=q 1=k 2=v (uniform)
        if (which == 0) bias *= 0.17677669529663687f;
        int h = (n0 & 127) >> 5;
        int d = (n0 & 31) + lr;
        f32x4 ci = {bias, bias, bias, bias};      // bias as MFMA C-init (same col per lane)
#pragma unroll
        for (int mt2 = 0; mt2 < 4; ++mt2) {
            f32x4 acc = ci;
#pragma unroll
            for (int kt = 0; kt < 4; ++kt)
                acc = __builtin_amdgcn_mfma_f32_16x16x32_bf16(a[mt2][kt], bw[kt], acc, 0, 0, 0);
            u32 r01 = pk2(acc[0], acc[1]);
            u32 r23 = pk2(acc[2], acc[3]);
            if (which == 2) {
                *(uint2*)&vT_s[(h * 32 + d) * VT_STR + mt2 * 16 + lg * 4] =
                    make_uint2(r01, r23);         // V^T, 4 contiguous token-cols
            } else {
                u16* dst = (which == 0) ? q_s : k_s;
                int rb = (h * 64 + mt2 * 16 + lg * 4) * QK_STR + d;
                dst[rb]              = (u16)r01;
                dst[rb + QK_STR]     = (u16)(r01 >> 16);
                dst[rb + 2 * QK_STR] = (u16)r23;
                dst[rb + 3 * QK_STR] = (u16)(r23 >> 16);
            }
        }
    }
    __syncthreads();

    // ---------------- stage 2: attention; wave = (mt, head-pair hp); no internal barrier ----
    float  invs[2][4];
    bf16x8 ap[2][2];
    u16* const pw = pB + w * 16 * PW_STR;         // this wave's private P/O region
#pragma unroll
    for (int hl = 0; hl < 2; ++hl) {
        int h = hp * 2 + hl;
        bf16x8 aq = *(const bf16x8*)&q_s[(h * 64 + mt * 16 + lr) * QK_STR + lg * 8];
        int eb = ((cls * 4 + h) * 4 + mt) * 4;
        f32x4 sc[4];
#pragma unroll
        for (int nt = 0; nt < 4; ++nt) {
            bf16x8 bk = *(const bf16x8*)&k_s[(h * 64 + nt * 16 + lr) * QK_STR + lg * 8];
            uint2 cv = ft2[(eb + nt) * 64 + lane];             // bias+mask, bf16-packed C-layout
            f32x4 ci = {bflo(cv.x), bfhi(cv.x), bflo(cv.y), bfhi(cv.y)};
            sc[nt] = __builtin_amdgcn_mfma_f32_16x16x32_bf16(aq, bk, ci, 0, 0, 0);
        }
#pragma unroll
        for (int j = 0; j < 4; ++j) {
            // no max-subtract: scores bounded (|qk| small, bias ~0.02), masked -> exp==0
            float p0 = __expf(sc[0][j]), p1 = __expf(sc[1][j]);
            float p2 = __expf(sc[2][j]), p3 = __expf(sc[3][j]);
            float sm = (p0 + p1) + (p2 + p3);
            sm += __shfl_xor(sm, 1);
            sm += __shfl_xor(sm, 2);
            sm += __shfl_xor(sm, 4);
            sm += __shfl_xor(sm, 8);
            invs[hl][j] = 1.f / sm;
            u32 r01 = pk2(p0, p1), r23 = pk2(p2, p3);
            u16* pr = pw + (lg * 4 + j) * PW_STR;
            pr[lr]      = (u16)r01;
            pr[lr + 16] = (u16)(r01 >> 16);
            pr[lr + 32] = (u16)r23;
            pr[lr + 48] = (u16)(r23 >> 16);
        }
        // transpose P back (own rows, same wave: in-order DS, no barrier)
        ap[hl][0] = *(const bf16x8*)&pw[lr * PW_STR + lg * 8];
        ap[hl][1] = *(const bf16x8*)&pw[lr * PW_STR + 32 + lg * 8];
    }
    // PV + O into the wave's own (fully consumed) P region
#pragma unroll
    for (int hl = 0; hl < 2; ++hl) {
        int h = hp * 2 + hl;
#pragma unroll
        for (int nt = 0; nt < 2; ++nt) {
            bf16x8 bv0 = *(const bf16x8*)&vT_s[(h * 32 + nt * 16 + lr) * VT_STR + lg * 8];
            bf16x8 bv1 = *(const bf16x8*)&vT_s[(h * 32 + nt * 16 + lr) * VT_STR + 32 + lg * 8];
            f32x4 z = {0.f, 0.f, 0.f, 0.f};
            f32x4 o = __builtin_amdgcn_mfma_f32_16x16x32_bf16(ap[hl][0], bv0, z, 0, 0, 0);
            o = __builtin_amdgcn_mfma_f32_16x16x32_bf16(ap[hl][1], bv1, o, 0, 0, 0);
            u32 r01 = pk2(o[0] * invs[hl][0], o[1] * invs[hl][1]);
            u32 r23 = pk2(o[2] * invs[hl][2], o[3] * invs[hl][3]);
            int cbase = hl * 32 + nt * 16 + lr;    // local col 0..63
            pw[(lg * 4 + 0) * PW_STR + cbase] = (u16)r01;
            pw[(lg * 4 + 1) * PW_STR + cbase] = (u16)(r01 >> 16);
            pw[(lg * 4 + 2) * PW_STR + cbase] = (u16)r23;
            pw[(lg * 4 + 3) * PW_STR + cbase] = (u16)(r23 >> 16);
        }
    }
    __syncthreads();

    // ---------------- stage 3: proj; O read from per-wave regions ----------------
    bf16x8 ao[4];
#pragma unroll
    for (int kt = 0; kt < 4; ++kt) {
        int srcw = (kt >> 1) * 4 + mt;            // region owner: wave (hp = kt>>1, same mt)
        ao[kt] = *(const bf16x8*)&pB[(srcw * 16 + lr) * PW_STR + (kt & 1) * 32 + lg * 8];
    }
    int obase[4];
#pragma unroll
    for (int j = 0; j < 4; ++j) {
        int tok = mt * 16 + lg * 4 + j;
        if (tok < 49) {
            int tr = tok / 7, tc = tok - tr * 7;
            int hs = wh * 7 + tr + 3; if (hs >= 112) hs -= 112;
            int cs = ww * 7 + tc + 3; if (cs >= 112) cs -= 112;
            obase[j] = ((b * 112 + hs) * 112 + cs) * 128;
        } else obase[j] = -1;
    }
#pragma unroll
    for (int tn = 0; tn < 4; ++tn) {
        int n0 = (hp * 4 + tn) * 16;
        bf16x8 bw[4];
#pragma unroll
        for (int kt = 0; kt < 4; ++kt)
            bw[kt] = *(const bf16x8*)&wproj[(n0 + lr) * 128 + kt * 32 + lg * 8];
        float bias = proj_b[n0 + lr];
        f32x4 acc = {bias, bias, bias, bias};     // bias as C-init
#pragma unroll
        for (int kt = 0; kt < 4; ++kt)
            acc = __builtin_amdgcn_mfma_f32_16x16x32_bf16(ao[kt], bw[kt], acc, 0, 0, 0);
#pragma unroll
        for (int j = 0; j < 4; ++j)
            if (obase[j] >= 0) out[obase[j] + n0 + lr] = acc[j];
    }
}

extern "C" void kernel_launch(void* const* d_in, const int* in_sizes, int n_in,
                              void* d_out, int out_size, void* d_ws, size_t ws_size,
                              hipStream_t stream) {
    (void)in_sizes; (void)n_in; (void)out_size; (void)ws_size;
    const float* x      = (const float*)d_in[0];
    const float* mask   = (const float*)d_in[1];
    const float* qkv_w  = (const float*)d_in[2];
    const float* qkv_b  = (const float*)d_in[3];
    const float* proj_w = (const float*)d_in[4];
    const float* proj_b = (const float*)d_in[5];
    const float* rpb    = (const float*)d_in[6];
    const int*   rel    = (const int*)d_in[7];
    float* out = (float*)d_out;

    u16*   ws16 = (u16*)d_ws;
    uint2* ftab = (uint2*)(ws16 + 65536);   // bytes [131072, 262144) — within proven footprint

    prep_kernel<<<dim3(192), dim3(256), 0, stream>>>(qkv_w, proj_w, mask, rpb, rel, ws16, ftab);
    swin_mfma<<<dim3(2048), dim3(512), 0, stream>>>(
        x, qkv_b, proj_b, ws16, ws16 + 49152, ftab, out);
}